// Round 13
// baseline (113.786 us; speedup 1.0000x reference)
//
#include <hip/hip_runtime.h>
#include <hip/hip_bf16.h>

// ---------------------------------------------------------------------------
// CrossAttention: out = softmax((x Wq)(ctx Wk)^T * scale) (ctx Wv) Wo
// B=2, N=M=2048, H=16, D=64, QD=INNER=1024. fp32 in/out, bf16 MFMA inside.
// R13: attention = R4 geometry (4 waves x 32 q-rows, grid 512) + R7 softmax
// (exp2 on pre-scaled Q, ones-MFMA row sums). Halves per-CU LDS read traffic
// (each staged K/V byte feeds 32 q-rows instead of 16). GEMMs/prep = R12.
// ---------------------------------------------------------------------------

typedef __attribute__((ext_vector_type(8))) __bf16    bf16x8;
typedef __attribute__((ext_vector_type(4))) __bf16    bf16x4;
typedef __attribute__((ext_vector_type(4))) float     f32x4;

#define B_    2
#define H_    16
#define N_    2048
#define M_    2048
#define D_    64
#define QD_   1024

// 0.125 * log2(e): folds softmax scale and exp->exp2 conversion into Q
#define QSCALE 0.18033688011112042f

// direct global->LDS async copy, 16B per lane; LDS dest = wave-uniform base + lane*16
__device__ __forceinline__ void gld16(const __bf16* g, __bf16* l) {
    __builtin_amdgcn_global_load_lds(
        (const __attribute__((address_space(1))) unsigned int*)(g),
        (__attribute__((address_space(3))) unsigned int*)(l), 16, 0, 0);
}

// ---------------------------------------------------------------------------
// prep: z<2 -> f32->bf16 convert of x/ctx; z>=2 -> weight transpose+convert.
// ---------------------------------------------------------------------------
__global__ __launch_bounds__(256) void prep(const float* __restrict__ x,
                                            const float* __restrict__ ctx,
                                            const float* __restrict__ w0,
                                            const float* __restrict__ w1,
                                            const float* __restrict__ w2,
                                            const float* __restrict__ w3,
                                            __bf16* __restrict__ xb,
                                            __bf16* __restrict__ cb,
                                            __bf16* __restrict__ t0,
                                            __bf16* __restrict__ t1,
                                            __bf16* __restrict__ t2,
                                            __bf16* __restrict__ t3) {
    __shared__ float tile[64][65];
    const int z = blockIdx.z;
    if (z < 2) {
        const float* src = z ? ctx : x;
        __bf16*      dst = z ? cb  : xb;
        const size_t base = (size_t)(blockIdx.y * 16 + blockIdx.x) * 16384;
#pragma unroll
        for (int p = 0; p < 16; ++p) {
            size_t i = base + p * 1024 + threadIdx.x * 4;
            float4 v = *reinterpret_cast<const float4*>(src + i);
            bf16x4 o;
            o.x = (__bf16)v.x; o.y = (__bf16)v.y; o.z = (__bf16)v.z; o.w = (__bf16)v.w;
            *reinterpret_cast<bf16x4*>(dst + i) = o;
        }
        return;
    }
    const int w = z - 2;
    const float* in = (w == 0) ? w0 : (w == 1) ? w1 : (w == 2) ? w2 : w3;
    __bf16*     out = (w == 0) ? t0 : (w == 1) ? t1 : (w == 2) ? t2 : t3;
    const int i0 = blockIdx.x * 64;
    const int o0 = blockIdx.y * 64;
    const int t  = threadIdx.x;
    const int r  = t >> 4;
    const int c4 = (t & 15) * 4;
#pragma unroll
    for (int p = 0; p < 4; ++p) {
        int row = p * 16 + r;
        float4 v = *reinterpret_cast<const float4*>(in + (size_t)(i0 + row) * QD_ + o0 + c4);
        tile[row][c4 + 0] = v.x; tile[row][c4 + 1] = v.y;
        tile[row][c4 + 2] = v.z; tile[row][c4 + 3] = v.w;
    }
    __syncthreads();
#pragma unroll
    for (int p = 0; p < 4; ++p) {
        int orow = p * 16 + r;
        bf16x4 o;
        o.x = (__bf16)tile[c4 + 0][orow];
        o.y = (__bf16)tile[c4 + 1][orow];
        o.z = (__bf16)tile[c4 + 2][orow];
        o.w = (__bf16)tile[c4 + 3][orow];
        *reinterpret_cast<bf16x4*>(out + (size_t)(o0 + orow) * QD_ + i0 + c4) = o;
    }
}

// ---------------------------------------------------------------------------
// gemm_qkv (R12): 128x128 tile, stage-ahead dbuf via gld16, XOR swizzle,
// LDS-pool repack epilogue (V transposed) -> coalesced bf16x8 stores.
// ---------------------------------------------------------------------------
__global__ __launch_bounds__(256) void gemm_qkv(const __bf16* __restrict__ xb,
                                                const __bf16* __restrict__ cb,
                                                const __bf16* __restrict__ Wtq,
                                                const __bf16* __restrict__ Wtk,
                                                const __bf16* __restrict__ Wtv,
                                                __bf16* __restrict__ Qb,
                                                __bf16* __restrict__ Kb,
                                                __bf16* __restrict__ Vt) {
    __shared__ __align__(16) __bf16 POOL[16384];   // 32 KB
    __bf16* const Al0 = POOL;
    __bf16* const Al1 = POOL + 4096;
    __bf16* const Bl0 = POOL + 8192;
    __bf16* const Bl1 = POOL + 12288;

    const int z = blockIdx.z;
    const __bf16* A_  = (z == 0) ? xb : cb;
    const __bf16* Bt_ = (z == 0) ? Wtq : (z == 1) ? Wtk : Wtv;

    const int tid  = threadIdx.x;
    const int wid  = tid >> 6;
    const int lane = tid & 63;
    const int l15  = lane & 15;
    const int lg   = lane >> 4;
    const int wr   = wid >> 1;
    const int wc   = wid & 1;
    const int rowBase = blockIdx.x * 128;
    const int colBase = blockIdx.y * 128;
    const int srow = wid * 32 + (lane >> 2);
    const int sg   = ((lane & 3) ^ ((srow >> 1) & 3)) * 8;  // pre-swizzled src granule
    const __bf16* Ag  = A_  + (size_t)(rowBase + srow) * QD_ + sg;
    const __bf16* Ag2 = Ag  + (size_t)16 * QD_;
    const __bf16* Bg  = Bt_ + (size_t)(colBase + srow) * QD_ + sg;
    const __bf16* Bg2 = Bg  + (size_t)16 * QD_;
    const int sOff  = (wid * 32) * 32;
    const int sOff2 = sOff + 16 * 32;
    int aoff[4], boff[4];
#pragma unroll
    for (int m = 0; m < 4; ++m) {
        int ra = wr * 64 + m * 16 + l15;
        int rb = wc * 64 + m * 16 + l15;
        aoff[m] = ra * 32 + ((lg ^ ((ra >> 1) & 3)) * 8);
        boff[m] = rb * 32 + ((lg ^ ((rb >> 1) & 3)) * 8);
    }
    f32x4 acc[4][4] = {};

#define GCOMPUTE(AL, BL)                                                                       \
    {                                                                                          \
        bf16x8 a[4], b[4];                                                                     \
        _Pragma("unroll")                                                                      \
        for (int m = 0; m < 4; ++m)                                                            \
            a[m] = *reinterpret_cast<const bf16x8*>(&(AL)[aoff[m]]);                           \
        _Pragma("unroll")                                                                      \
        for (int n = 0; n < 4; ++n)                                                            \
            b[n] = *reinterpret_cast<const bf16x8*>(&(BL)[boff[n]]);                           \
        _Pragma("unroll")                                                                      \
        for (int m = 0; m < 4; ++m)                                                            \
            _Pragma("unroll")                                                                  \
            for (int n = 0; n < 4; ++n)                                                        \
                acc[m][n] = __builtin_amdgcn_mfma_f32_16x16x32_bf16(a[m], b[n], acc[m][n], 0, 0, 0); \
    }

    gld16(Ag,  Al0 + sOff);
    gld16(Ag2, Al0 + sOff2);
    gld16(Bg,  Bl0 + sOff);
    gld16(Bg2, Bl0 + sOff2);
    __syncthreads();
    for (int t = 0; t < 32; t += 2) {
        if (t + 1 < 32) {
            int kn = (t + 1) * 32;
            gld16(Ag + kn,  Al1 + sOff);
            gld16(Ag2 + kn, Al1 + sOff2);
            gld16(Bg + kn,  Bl1 + sOff);
            gld16(Bg2 + kn, Bl1 + sOff2);
        }
        GCOMPUTE(Al0, Bl0)
        __syncthreads();
        if (t + 2 < 32) {
            int kn = (t + 2) * 32;
            gld16(Ag + kn,  Al0 + sOff);
            gld16(Ag2 + kn, Al0 + sOff2);
            gld16(Bg + kn,  Bl0 + sOff);
            gld16(Bg2 + kn, Bl0 + sOff2);
        }
        GCOMPUTE(Al1, Bl1)
        __syncthreads();
    }
#undef GCOMPUTE

    // epilogue: repack into POOL (V transposed), then coalesced stores
#pragma unroll
    for (int m = 0; m < 4; ++m)
#pragma unroll
        for (int n = 0; n < 4; ++n)
#pragma unroll
            for (int r = 0; r < 4; ++r) {
                float v = acc[m][n][r];
                if (z == 0) v *= QSCALE;
                int rl = wr * 64 + m * 16 + lg * 4 + r;
                int cl = wc * 64 + n * 16 + l15;
                if (z == 2) POOL[cl * 128 + rl] = (__bf16)v;   // [d-col][token]
                else        POOL[rl * 128 + cl] = (__bf16)v;   // [token][d-col]
            }
    __syncthreads();

    const int prow0 = tid >> 4;         // 0..15
    const int pcol  = (tid & 15) * 8;   // 0..120
#pragma unroll
    for (int s = 0; s < 8; ++s) {
        int row = s * 16 + prow0;
        bf16x8 vv = *reinterpret_cast<const bf16x8*>(&POOL[row * 128 + pcol]);
        if (z == 2) {
            int cc = colBase + row, rr = rowBase + pcol;
            int b_ = rr >> 11, mm = rr & 2047, hh = cc >> 6, dd = cc & 63;
            *reinterpret_cast<bf16x8*>(&Vt[((size_t)(b_ * H_ + hh) * D_ + dd) * M_ + mm]) = vv;
        } else {
            int rr = rowBase + row, cc = colBase + pcol;
            int b_ = rr >> 11, nn = rr & 2047, hh = cc >> 6, dd = cc & 63;
            __bf16* dst = (z == 0) ? Qb : Kb;
            *reinterpret_cast<bf16x8*>(&dst[((size_t)(b_ * H_ + hh) * N_ + nn) * D_ + dd]) = vv;
        }
    }
}

// ---------------------------------------------------------------------------
// gemm_out (R12): 128x64 tile, stage-ahead dbuf + swizzle, f32 repack.
// ---------------------------------------------------------------------------
__global__ __launch_bounds__(256) void gemm_out(const __bf16* __restrict__ AO,
                                                const __bf16* __restrict__ Wto,
                                                float* __restrict__ out) {
    __shared__ __align__(16) __bf16 POOL[16384];   // 32 KB
    __bf16* const Al0 = POOL;
    __bf16* const Al1 = POOL + 4096;
    __bf16* const Bl0 = POOL + 8192;
    __bf16* const Bl1 = POOL + 10240;

    const int tid  = threadIdx.x;
    const int wid  = tid >> 6;
    const int lane = tid & 63;
    const int l15  = lane & 15;
    const int lg   = lane >> 4;
    const int wr   = wid >> 1;
    const int wc   = wid & 1;
    const int rowBase = blockIdx.x * 128;
    const int colBase = blockIdx.y * 64;
    const int srowA = wid * 32 + (lane >> 2);
    const int srowB = wid * 16 + (lane >> 2);
    const int sgA   = ((lane & 3) ^ ((srowA >> 1) & 3)) * 8;
    const int sgB   = ((lane & 3) ^ ((srowB >> 1) & 3)) * 8;
    const __bf16* Ag  = AO  + (size_t)(rowBase + srowA) * QD_ + sgA;
    const __bf16* Ag2 = Ag  + (size_t)16 * QD_;
    const __bf16* Bg  = Wto + (size_t)(colBase + srowB) * QD_ + sgB;
    const int sOffA  = (wid * 32) * 32;
    const int sOffA2 = sOffA + 16 * 32;
    const int sOffB  = (wid * 16) * 32;
    int aoff[4], boff[2];
#pragma unroll
    for (int m = 0; m < 4; ++m) {
        int ra = wr * 64 + m * 16 + l15;
        aoff[m] = ra * 32 + ((lg ^ ((ra >> 1) & 3)) * 8);
    }
#pragma unroll
    for (int n = 0; n < 2; ++n) {
        int rb = wc * 32 + n * 16 + l15;
        boff[n] = rb * 32 + ((lg ^ ((rb >> 1) & 3)) * 8);
    }
    f32x4 acc[4][2] = {};

#define GCOMPUTE2(AL, BL)                                                                      \
    {                                                                                          \
        bf16x8 a[4], b[2];                                                                     \
        _Pragma("unroll")                                                                      \
        for (int m = 0; m < 4; ++m)                                                            \
            a[m] = *reinterpret_cast<const bf16x8*>(&(AL)[aoff[m]]);                           \
        _Pragma("unroll")                                                                      \
        for (int n = 0; n < 2; ++n)                                                            \
            b[n] = *reinterpret_cast<const bf16x8*>(&(BL)[boff[n]]);                           \
        _Pragma("unroll")                                                                      \
        for (int m = 0; m < 4; ++m)                                                            \
            _Pragma("unroll")                                                                  \
            for (int n = 0; n < 2; ++n)                                                        \
                acc[m][n] = __builtin_amdgcn_mfma_f32_16x16x32_bf16(a[m], b[n], acc[m][n], 0, 0, 0); \
    }

    gld16(Ag,  Al0 + sOffA);
    gld16(Ag2, Al0 + sOffA2);
    gld16(Bg,  Bl0 + sOffB);
    __syncthreads();
    for (int t = 0; t < 32; t += 2) {
        if (t + 1 < 32) {
            int kn = (t + 1) * 32;
            gld16(Ag + kn,  Al1 + sOffA);
            gld16(Ag2 + kn, Al1 + sOffA2);
            gld16(Bg + kn,  Bl1 + sOffB);
        }
        GCOMPUTE2(Al0, Bl0)
        __syncthreads();
        if (t + 2 < 32) {
            int kn = (t + 2) * 32;
            gld16(Ag + kn,  Al0 + sOffA);
            gld16(Ag2 + kn, Al0 + sOffA2);
            gld16(Bg + kn,  Bl0 + sOffB);
        }
        GCOMPUTE2(Al1, Bl1)
        __syncthreads();
    }
#undef GCOMPUTE2

    float* FP = reinterpret_cast<float*>(POOL);
#pragma unroll
    for (int m = 0; m < 4; ++m)
#pragma unroll
        for (int n = 0; n < 2; ++n)
#pragma unroll
            for (int r = 0; r < 4; ++r) {
                int rl = wr * 64 + m * 16 + lg * 4 + r;
                int cl = wc * 32 + n * 16 + l15;
                FP[rl * 64 + cl] = acc[m][n][r];
            }
    __syncthreads();
    const int prow0 = tid >> 4;
    const int pcol4 = (tid & 15) * 4;
#pragma unroll
    for (int s = 0; s < 8; ++s) {
        int row = s * 16 + prow0;
        float4 vv = *reinterpret_cast<const float4*>(&FP[row * 64 + pcol4]);
        *reinterpret_cast<float4*>(&out[(size_t)(rowBase + row) * QD_ + colBase + pcol4]) = vv;
    }
}

// ---------------------------------------------------------------------------
// Attention R13: grid 512 (XCD-swizzled), 4 waves x 32 q-rows (256 threads).
// K/V LDS double-buffered (32 KB), KVBLK=64, R4's staging swizzle (verified).
// R7 softmax: exp2 on pre-scaled Q, ones-MFMA row sums (ors0/ors1).
// Each staged K/V byte now feeds 32 q-rows: per-CU LDS read traffic halved.
// ---------------------------------------------------------------------------
__global__ __launch_bounds__(256) void attn_kernel(const __bf16* __restrict__ Q,
                                                   const __bf16* __restrict__ K,
                                                   const __bf16* __restrict__ Vt,
                                                   __bf16* __restrict__ AO) {
    __shared__ __align__(16) __bf16 Klds[2][4096];
    __shared__ __align__(16) __bf16 Vlds[2][4096];

    const int logical = (blockIdx.x & 7) * 64 + (blockIdx.x >> 3);
    const int qt   = logical & 15;
    const int bh   = logical >> 4;
    const int b    = bh >> 4;
    const int h    = bh & 15;
    const int wid  = threadIdx.x >> 6;
    const int lane = threadIdx.x & 63;
    const int l15  = lane & 15;
    const int lg   = lane >> 4;
    const int qbase = qt * 128 + wid * 32;

    const __bf16* Qp = Q  + ((size_t)bh * N_ + qbase) * D_;
    const __bf16* Kp = K  + (size_t)bh * M_ * D_;
    const __bf16* Vp = Vt + (size_t)bh * D_ * M_;

    // ---- staging geometry (R4, verified): per wave 2 K + 2 V gld16 ----
    const int srow = (wid << 4) + (lane >> 3);
    const int scol = (lane & 7) << 3;
    const int sk0  = (lane >> 3) & 3;
    const int sk1  = sk0 | 4;
    const int sv   = lane >> 3;
    const int kc0  = scol ^ (sk0 << 3);
    const int kc1  = scol ^ (sk1 << 3);
    const int vc   = scol ^ (sv  << 3);
    __bf16* kl0 = &Klds[0][wid * 1024];
    __bf16* kl1 = &Klds[1][wid * 1024];
    __bf16* vl0 = &Vlds[0][wid * 1024];
    __bf16* vl1 = &Vlds[1][wid * 1024];

#define STAGE(KL, VL, KV0)                                                     \
    gld16(Kp + (size_t)((KV0) + srow)     * D_ + kc0, (KL));                   \
    gld16(Kp + (size_t)((KV0) + srow + 8) * D_ + kc1, (KL) + 512);             \
    gld16(Vp + (size_t)(srow)     * M_ + (KV0) + vc,  (VL));                   \
    gld16(Vp + (size_t)(srow + 8) * M_ + (KV0) + vc,  (VL) + 512);

    // ---- read geometry (R4, verified) ----
    const int rm0 = ((l15 >> 2) * 8) + (l15 & 3);
    const int skq = (l15 & 3) | (((l15 >> 2) & 1) << 2);
    const int svq = l15 & 7;
    const int ak00 = rm0 * 64 + (( 0 + lg * 8) ^ (skq << 3));
    const int ak01 = rm0 * 64 + ((32 + lg * 8) ^ (skq << 3));
    const int ak10 = ak00 + 256;
    const int ak11 = ak01 + 256;
    const int av0 = l15 * 64 + (( 0 + lg * 8) ^ (svq << 3));
    const int av1 = l15 * 64 + ((32 + lg * 8) ^ (svq << 3));

    // Q fragments (B-operand), two q-groups of 16 rows
    bf16x8 qf00 = *reinterpret_cast<const bf16x8*>(Qp + (size_t)(l15)      * D_ +      lg * 8);
    bf16x8 qf01 = *reinterpret_cast<const bf16x8*>(Qp + (size_t)(l15)      * D_ + 32 + lg * 8);
    bf16x8 qf10 = *reinterpret_cast<const bf16x8*>(Qp + (size_t)(16 + l15) * D_ +      lg * 8);
    bf16x8 qf11 = *reinterpret_cast<const bf16x8*>(Qp + (size_t)(16 + l15) * D_ + 32 + lg * 8);

    bf16x8 onesf;
#pragma unroll
    for (int j = 0; j < 8; ++j) onesf[j] = (__bf16)1.0f;

    f32x4 o00 = {}, o01 = {}, o10 = {}, o11 = {};
    f32x4 o20 = {}, o21 = {}, o30 = {}, o31 = {};
    f32x4 ors0 = {}, ors1 = {};

#define COMPUTE(KB, VB, KOFF, AV)                                                               \
    {                                                                                           \
        bf16x8 k00 = *reinterpret_cast<const bf16x8*>((KB) + ak00 + (KOFF));                    \
        bf16x8 k01 = *reinterpret_cast<const bf16x8*>((KB) + ak01 + (KOFF));                    \
        bf16x8 k10 = *reinterpret_cast<const bf16x8*>((KB) + ak10 + (KOFF));                    \
        bf16x8 k11 = *reinterpret_cast<const bf16x8*>((KB) + ak11 + (KOFF));                    \
        bf16x8 v0  = *reinterpret_cast<const bf16x8*>((VB) + (AV));                             \
        bf16x8 v1  = *reinterpret_cast<const bf16x8*>((VB) + (AV) + 1024);                      \
        bf16x8 v2  = *reinterpret_cast<const bf16x8*>((VB) + (AV) + 2048);                      \
        bf16x8 v3  = *reinterpret_cast<const bf16x8*>((VB) + (AV) + 3072);                      \
        f32x4 s00 = {}, s01 = {}, s10 = {}, s11 = {};                                           \
        s00 = __builtin_amdgcn_mfma_f32_16x16x32_bf16(k00, qf00, s00, 0, 0, 0);                 \
        s00 = __builtin_amdgcn_mfma_f32_16x16x32_bf16(k01, qf01, s00, 0, 0, 0);                 \
        s01 = __builtin_amdgcn_mfma_f32_16x16x32_bf16(k00, qf10, s01, 0, 0, 0);                 \
        s01 = __builtin_amdgcn_mfma_f32_16x16x32_bf16(k01, qf11, s01, 0, 0, 0);                 \
        s10 = __builtin_amdgcn_mfma_f32_16x16x32_bf16(k10, qf00, s10, 0, 0, 0);                 \
        s10 = __builtin_amdgcn_mfma_f32_16x16x32_bf16(k11, qf01, s10, 0, 0, 0);                 \
        s11 = __builtin_amdgcn_mfma_f32_16x16x32_bf16(k10, qf10, s11, 0, 0, 0);                 \
        s11 = __builtin_amdgcn_mfma_f32_16x16x32_bf16(k11, qf11, s11, 0, 0, 0);                 \
        bf16x8 pf0, pf1;                                                                        \
        pf0[0] = (__bf16)__builtin_amdgcn_exp2f(s00[0]);                                        \
        pf0[1] = (__bf16)__builtin_amdgcn_exp2f(s00[1]);                                        \
        pf0[2] = (__bf16)__builtin_amdgcn_exp2f(s00[2]);                                        \
        pf0[3] = (__bf16)__builtin_amdgcn_exp2f(s00[3]);                                        \
        pf0[4] = (__bf16)__builtin_amdgcn_exp2f(s10[0]);                                        \
        pf0[5] = (__bf16)__builtin_amdgcn_exp2f(s10[1]);                                        \
        pf0[6] = (__bf16)__builtin_amdgcn_exp2f(s10[2]);                                        \
        pf0[7] = (__bf16)__builtin_amdgcn_exp2f(s10[3]);                                        \
        pf1[0] = (__bf16)__builtin_amdgcn_exp2f(s01[0]);                                        \
        pf1[1] = (__bf16)__builtin_amdgcn_exp2f(s01[1]);                                        \
        pf1[2] = (__bf16)__builtin_amdgcn_exp2f(s01[2]);                                        \
        pf1[3] = (__bf16)__builtin_amdgcn_exp2f(s01[3]);                                        \
        pf1[4] = (__bf16)__builtin_amdgcn_exp2f(s11[0]);                                        \
        pf1[5] = (__bf16)__builtin_amdgcn_exp2f(s11[1]);                                        \
        pf1[6] = (__bf16)__builtin_amdgcn_exp2f(s11[2]);                                        \
        pf1[7] = (__bf16)__builtin_amdgcn_exp2f(s11[3]);                                        \
        ors0 = __builtin_amdgcn_mfma_f32_16x16x32_bf16(pf0, onesf, ors0, 0, 0, 0);              \
        ors1 = __builtin_amdgcn_mfma_f32_16x16x32_bf16(pf1, onesf, ors1, 0, 0, 0);              \
        o00 = __builtin_amdgcn_mfma_f32_16x16x32_bf16(pf0, v0, o00, 0, 0, 0);                   \
        o01 = __builtin_amdgcn_mfma_f32_16x16x32_bf16(pf1, v0, o01, 0, 0, 0);                   \
        o10 = __builtin_amdgcn_mfma_f32_16x16x32_bf16(pf0, v1, o10, 0, 0, 0);                   \
        o11 = __builtin_amdgcn_mfma_f32_16x16x32_bf16(pf1, v1, o11, 0, 0, 0);                   \
        o20 = __builtin_amdgcn_mfma_f32_16x16x32_bf16(pf0, v2, o20, 0, 0, 0);                   \
        o21 = __builtin_amdgcn_mfma_f32_16x16x32_bf16(pf1, v2, o21, 0, 0, 0);                   \
        o30 = __builtin_amdgcn_mfma_f32_16x16x32_bf16(pf0, v3, o30, 0, 0, 0);                   \
        o31 = __builtin_amdgcn_mfma_f32_16x16x32_bf16(pf1, v3, o31, 0, 0, 0);                   \
    }

    STAGE(kl0, vl0, 0)
    __syncthreads();

    for (int t = 0; t < 32; t += 2) {
        if (t + 1 < 32) { STAGE(kl1, vl1, (t + 1) * 64) }
        COMPUTE(Klds[0], Vlds[0], 0,    av0)
        COMPUTE(Klds[0], Vlds[0], 2048, av1)
        __syncthreads();
        if (t + 2 < 32) { STAGE(kl0, vl0, (t + 2) * 64) }
        COMPUTE(Klds[1], Vlds[1], 0,    av0)
        COMPUTE(Klds[1], Vlds[1], 2048, av1)
        __syncthreads();
    }
#undef STAGE
#undef COMPUTE

    // lane holds O[q-group0: qbase+lg*4+r][d=n*16+l15] in o_n0[r] (sum ors0[r]),
    //            O[q-group1: qbase+16+lg*4+r][...]     in o_n1[r] (sum ors1[r]).
#pragma unroll
    for (int r = 0; r < 4; ++r) {
        float i0 = 1.0f / ors0[r];
        float i1 = 1.0f / ors1[r];
        size_t row0 = ((size_t)b * N_ + qbase + lg * 4 + r) * QD_ + h * D_ + l15;
        size_t row1 = ((size_t)b * N_ + qbase + 16 + lg * 4 + r) * QD_ + h * D_ + l15;
        AO[row0 +  0] = (__bf16)(o00[r] * i0);
        AO[row0 + 16] = (__bf16)(o10[r] * i0);
        AO[row0 + 32] = (__bf16)(o20[r] * i0);
        AO[row0 + 48] = (__bf16)(o30[r] * i0);
        AO[row1 +  0] = (__bf16)(o01[r] * i1);
        AO[row1 + 16] = (__bf16)(o11[r] * i1);
        AO[row1 + 32] = (__bf16)(o21[r] * i1);
        AO[row1 + 48] = (__bf16)(o31[r] * i1);
    }
}

// ---------------------------------------------------------------------------
extern "C" void kernel_launch(void* const* d_in, const int* in_sizes, int n_in,
                              void* d_out, int out_size, void* d_ws, size_t ws_size,
                              hipStream_t stream) {
    const float* x   = (const float*)d_in[0];
    const float* ctx = (const float*)d_in[1];
    const float* Wq  = (const float*)d_in[2];
    const float* Wk  = (const float*)d_in[3];
    const float* Wv  = (const float*)d_in[4];
    const float* Wo  = (const float*)d_in[5];

    char* ws = (char*)d_ws;
    __bf16* xb  = (__bf16*)(ws);                      // 0-8 MB
    __bf16* cb  = (__bf16*)(ws + (8u  << 20));        // 8-16 MB
    __bf16* Wtq = (__bf16*)(ws + (16u << 20));        // 16-18 MB
    __bf16* Wtk = (__bf16*)(ws + (18u << 20));        // 18-20
    __bf16* Wtv = (__bf16*)(ws + (20u << 20));        // 20-22
    __bf16* Wto = (__bf16*)(ws + (22u << 20));        // 22-24
    __bf16* Qb  = (__bf16*)(ws + (24u << 20));        // 24-32  [bh][2048][64], pre-scaled
    __bf16* Kb  = (__bf16*)(ws + (32u << 20));        // 32-40  [bh][2048][64]
    __bf16* Vt  = (__bf16*)(ws + (40u << 20));        // 40-48  [bh][64][2048]
    __bf16* AO  = (__bf16*)(ws + (48u << 20));        // 48-56  [4096][1024]

    prep<<<dim3(16, 16, 6), 256, 0, stream>>>(x, ctx, Wq, Wk, Wv, Wo,
                                              xb, cb, Wtq, Wtk, Wtv, Wto);
    gemm_qkv<<<dim3(32, 8, 3), 256, 0, stream>>>(xb, cb, Wtq, Wtk, Wtv, Qb, Kb, Vt);
    attn_kernel<<<512, 256, 0, stream>>>(Qb, Kb, Vt, AO);
    gemm_out<<<dim3(32, 16), 256, 0, stream>>>(AO, Wto, (float*)d_out);
}

// Round 14
// 105.887 us; speedup vs baseline: 1.0746x; 1.0746x over previous
//
#include <hip/hip_runtime.h>
#include <hip/hip_bf16.h>

// ---------------------------------------------------------------------------
// CrossAttention: out = softmax((x Wq)(ctx Wk)^T * scale) (ctx Wv) Wo
// B=2, N=M=2048, H=16, D=64, QD=INNER=1024. fp32 in/out, bf16 MFMA inside.
// R14: attention = in-block KV-split: 512 threads (grid 512, 16 waves/CU cap
// like R12) organized as 2 groups x 4 waves; each wave owns 32 q-rows (R13's
// 2:1 MFMA:ds_read ratio), each group sweeps half the KV range against its
// own double-buffered K/V tiles (64 KB LDS). f32 partial combine via LDS.
// GEMMs/prep unchanged from R12.
// ---------------------------------------------------------------------------

typedef __attribute__((ext_vector_type(8))) __bf16    bf16x8;
typedef __attribute__((ext_vector_type(4))) __bf16    bf16x4;
typedef __attribute__((ext_vector_type(4))) float     f32x4;

#define B_    2
#define H_    16
#define N_    2048
#define M_    2048
#define D_    64
#define QD_   1024

// 0.125 * log2(e): folds softmax scale and exp->exp2 conversion into Q
#define QSCALE 0.18033688011112042f

// direct global->LDS async copy, 16B per lane; LDS dest = wave-uniform base + lane*16
__device__ __forceinline__ void gld16(const __bf16* g, __bf16* l) {
    __builtin_amdgcn_global_load_lds(
        (const __attribute__((address_space(1))) unsigned int*)(g),
        (__attribute__((address_space(3))) unsigned int*)(l), 16, 0, 0);
}

// ---------------------------------------------------------------------------
// prep: z<2 -> f32->bf16 convert of x/ctx; z>=2 -> weight transpose+convert.
// ---------------------------------------------------------------------------
__global__ __launch_bounds__(256) void prep(const float* __restrict__ x,
                                            const float* __restrict__ ctx,
                                            const float* __restrict__ w0,
                                            const float* __restrict__ w1,
                                            const float* __restrict__ w2,
                                            const float* __restrict__ w3,
                                            __bf16* __restrict__ xb,
                                            __bf16* __restrict__ cb,
                                            __bf16* __restrict__ t0,
                                            __bf16* __restrict__ t1,
                                            __bf16* __restrict__ t2,
                                            __bf16* __restrict__ t3) {
    __shared__ float tile[64][65];
    const int z = blockIdx.z;
    if (z < 2) {
        const float* src = z ? ctx : x;
        __bf16*      dst = z ? cb  : xb;
        const size_t base = (size_t)(blockIdx.y * 16 + blockIdx.x) * 16384;
#pragma unroll
        for (int p = 0; p < 16; ++p) {
            size_t i = base + p * 1024 + threadIdx.x * 4;
            float4 v = *reinterpret_cast<const float4*>(src + i);
            bf16x4 o;
            o.x = (__bf16)v.x; o.y = (__bf16)v.y; o.z = (__bf16)v.z; o.w = (__bf16)v.w;
            *reinterpret_cast<bf16x4*>(dst + i) = o;
        }
        return;
    }
    const int w = z - 2;
    const float* in = (w == 0) ? w0 : (w == 1) ? w1 : (w == 2) ? w2 : w3;
    __bf16*     out = (w == 0) ? t0 : (w == 1) ? t1 : (w == 2) ? t2 : t3;
    const int i0 = blockIdx.x * 64;
    const int o0 = blockIdx.y * 64;
    const int t  = threadIdx.x;
    const int r  = t >> 4;
    const int c4 = (t & 15) * 4;
#pragma unroll
    for (int p = 0; p < 4; ++p) {
        int row = p * 16 + r;
        float4 v = *reinterpret_cast<const float4*>(in + (size_t)(i0 + row) * QD_ + o0 + c4);
        tile[row][c4 + 0] = v.x; tile[row][c4 + 1] = v.y;
        tile[row][c4 + 2] = v.z; tile[row][c4 + 3] = v.w;
    }
    __syncthreads();
#pragma unroll
    for (int p = 0; p < 4; ++p) {
        int orow = p * 16 + r;
        bf16x4 o;
        o.x = (__bf16)tile[c4 + 0][orow];
        o.y = (__bf16)tile[c4 + 1][orow];
        o.z = (__bf16)tile[c4 + 2][orow];
        o.w = (__bf16)tile[c4 + 3][orow];
        *reinterpret_cast<bf16x4*>(out + (size_t)(o0 + orow) * QD_ + i0 + c4) = o;
    }
}

// ---------------------------------------------------------------------------
// gemm_qkv (R12): 128x128 tile, stage-ahead dbuf via gld16, XOR swizzle,
// LDS-pool repack epilogue (V transposed) -> coalesced bf16x8 stores.
// ---------------------------------------------------------------------------
__global__ __launch_bounds__(256) void gemm_qkv(const __bf16* __restrict__ xb,
                                                const __bf16* __restrict__ cb,
                                                const __bf16* __restrict__ Wtq,
                                                const __bf16* __restrict__ Wtk,
                                                const __bf16* __restrict__ Wtv,
                                                __bf16* __restrict__ Qb,
                                                __bf16* __restrict__ Kb,
                                                __bf16* __restrict__ Vt) {
    __shared__ __align__(16) __bf16 POOL[16384];   // 32 KB
    __bf16* const Al0 = POOL;
    __bf16* const Al1 = POOL + 4096;
    __bf16* const Bl0 = POOL + 8192;
    __bf16* const Bl1 = POOL + 12288;

    const int z = blockIdx.z;
    const __bf16* A_  = (z == 0) ? xb : cb;
    const __bf16* Bt_ = (z == 0) ? Wtq : (z == 1) ? Wtk : Wtv;

    const int tid  = threadIdx.x;
    const int wid  = tid >> 6;
    const int lane = tid & 63;
    const int l15  = lane & 15;
    const int lg   = lane >> 4;
    const int wr   = wid >> 1;
    const int wc   = wid & 1;
    const int rowBase = blockIdx.x * 128;
    const int colBase = blockIdx.y * 128;
    const int srow = wid * 32 + (lane >> 2);
    const int sg   = ((lane & 3) ^ ((srow >> 1) & 3)) * 8;  // pre-swizzled src granule
    const __bf16* Ag  = A_  + (size_t)(rowBase + srow) * QD_ + sg;
    const __bf16* Ag2 = Ag  + (size_t)16 * QD_;
    const __bf16* Bg  = Bt_ + (size_t)(colBase + srow) * QD_ + sg;
    const __bf16* Bg2 = Bg  + (size_t)16 * QD_;
    const int sOff  = (wid * 32) * 32;
    const int sOff2 = sOff + 16 * 32;
    int aoff[4], boff[4];
#pragma unroll
    for (int m = 0; m < 4; ++m) {
        int ra = wr * 64 + m * 16 + l15;
        int rb = wc * 64 + m * 16 + l15;
        aoff[m] = ra * 32 + ((lg ^ ((ra >> 1) & 3)) * 8);
        boff[m] = rb * 32 + ((lg ^ ((rb >> 1) & 3)) * 8);
    }
    f32x4 acc[4][4] = {};

#define GCOMPUTE(AL, BL)                                                                       \
    {                                                                                          \
        bf16x8 a[4], b[4];                                                                     \
        _Pragma("unroll")                                                                      \
        for (int m = 0; m < 4; ++m)                                                            \
            a[m] = *reinterpret_cast<const bf16x8*>(&(AL)[aoff[m]]);                           \
        _Pragma("unroll")                                                                      \
        for (int n = 0; n < 4; ++n)                                                            \
            b[n] = *reinterpret_cast<const bf16x8*>(&(BL)[boff[n]]);                           \
        _Pragma("unroll")                                                                      \
        for (int m = 0; m < 4; ++m)                                                            \
            _Pragma("unroll")                                                                  \
            for (int n = 0; n < 4; ++n)                                                        \
                acc[m][n] = __builtin_amdgcn_mfma_f32_16x16x32_bf16(a[m], b[n], acc[m][n], 0, 0, 0); \
    }

    gld16(Ag,  Al0 + sOff);
    gld16(Ag2, Al0 + sOff2);
    gld16(Bg,  Bl0 + sOff);
    gld16(Bg2, Bl0 + sOff2);
    __syncthreads();
    for (int t = 0; t < 32; t += 2) {
        if (t + 1 < 32) {
            int kn = (t + 1) * 32;
            gld16(Ag + kn,  Al1 + sOff);
            gld16(Ag2 + kn, Al1 + sOff2);
            gld16(Bg + kn,  Bl1 + sOff);
            gld16(Bg2 + kn, Bl1 + sOff2);
        }
        GCOMPUTE(Al0, Bl0)
        __syncthreads();
        if (t + 2 < 32) {
            int kn = (t + 2) * 32;
            gld16(Ag + kn,  Al0 + sOff);
            gld16(Ag2 + kn, Al0 + sOff2);
            gld16(Bg + kn,  Bl0 + sOff);
            gld16(Bg2 + kn, Bl0 + sOff2);
        }
        GCOMPUTE(Al1, Bl1)
        __syncthreads();
    }
#undef GCOMPUTE

    // epilogue: repack into POOL (V transposed), then coalesced stores
#pragma unroll
    for (int m = 0; m < 4; ++m)
#pragma unroll
        for (int n = 0; n < 4; ++n)
#pragma unroll
            for (int r = 0; r < 4; ++r) {
                float v = acc[m][n][r];
                if (z == 0) v *= QSCALE;
                int rl = wr * 64 + m * 16 + lg * 4 + r;
                int cl = wc * 64 + n * 16 + l15;
                if (z == 2) POOL[cl * 128 + rl] = (__bf16)v;   // [d-col][token]
                else        POOL[rl * 128 + cl] = (__bf16)v;   // [token][d-col]
            }
    __syncthreads();

    const int prow0 = tid >> 4;         // 0..15
    const int pcol  = (tid & 15) * 8;   // 0..120
#pragma unroll
    for (int s = 0; s < 8; ++s) {
        int row = s * 16 + prow0;
        bf16x8 vv = *reinterpret_cast<const bf16x8*>(&POOL[row * 128 + pcol]);
        if (z == 2) {
            int cc = colBase + row, rr = rowBase + pcol;
            int b_ = rr >> 11, mm = rr & 2047, hh = cc >> 6, dd = cc & 63;
            *reinterpret_cast<bf16x8*>(&Vt[((size_t)(b_ * H_ + hh) * D_ + dd) * M_ + mm]) = vv;
        } else {
            int rr = rowBase + row, cc = colBase + pcol;
            int b_ = rr >> 11, nn = rr & 2047, hh = cc >> 6, dd = cc & 63;
            __bf16* dst = (z == 0) ? Qb : Kb;
            *reinterpret_cast<bf16x8*>(&dst[((size_t)(b_ * H_ + hh) * N_ + nn) * D_ + dd]) = vv;
        }
    }
}

// ---------------------------------------------------------------------------
// gemm_out (R12): 128x64 tile, stage-ahead dbuf + swizzle, f32 repack.
// ---------------------------------------------------------------------------
__global__ __launch_bounds__(256) void gemm_out(const __bf16* __restrict__ AO,
                                                const __bf16* __restrict__ Wto,
                                                float* __restrict__ out) {
    __shared__ __align__(16) __bf16 POOL[16384];   // 32 KB
    __bf16* const Al0 = POOL;
    __bf16* const Al1 = POOL + 4096;
    __bf16* const Bl0 = POOL + 8192;
    __bf16* const Bl1 = POOL + 10240;

    const int tid  = threadIdx.x;
    const int wid  = tid >> 6;
    const int lane = tid & 63;
    const int l15  = lane & 15;
    const int lg   = lane >> 4;
    const int wr   = wid >> 1;
    const int wc   = wid & 1;
    const int rowBase = blockIdx.x * 128;
    const int colBase = blockIdx.y * 64;
    const int srowA = wid * 32 + (lane >> 2);
    const int srowB = wid * 16 + (lane >> 2);
    const int sgA   = ((lane & 3) ^ ((srowA >> 1) & 3)) * 8;
    const int sgB   = ((lane & 3) ^ ((srowB >> 1) & 3)) * 8;
    const __bf16* Ag  = AO  + (size_t)(rowBase + srowA) * QD_ + sgA;
    const __bf16* Ag2 = Ag  + (size_t)16 * QD_;
    const __bf16* Bg  = Wto + (size_t)(colBase + srowB) * QD_ + sgB;
    const int sOffA  = (wid * 32) * 32;
    const int sOffA2 = sOffA + 16 * 32;
    const int sOffB  = (wid * 16) * 32;
    int aoff[4], boff[2];
#pragma unroll
    for (int m = 0; m < 4; ++m) {
        int ra = wr * 64 + m * 16 + l15;
        aoff[m] = ra * 32 + ((lg ^ ((ra >> 1) & 3)) * 8);
    }
#pragma unroll
    for (int n = 0; n < 2; ++n) {
        int rb = wc * 32 + n * 16 + l15;
        boff[n] = rb * 32 + ((lg ^ ((rb >> 1) & 3)) * 8);
    }
    f32x4 acc[4][2] = {};

#define GCOMPUTE2(AL, BL)                                                                      \
    {                                                                                          \
        bf16x8 a[4], b[2];                                                                     \
        _Pragma("unroll")                                                                      \
        for (int m = 0; m < 4; ++m)                                                            \
            a[m] = *reinterpret_cast<const bf16x8*>(&(AL)[aoff[m]]);                           \
        _Pragma("unroll")                                                                      \
        for (int n = 0; n < 2; ++n)                                                            \
            b[n] = *reinterpret_cast<const bf16x8*>(&(BL)[boff[n]]);                           \
        _Pragma("unroll")                                                                      \
        for (int m = 0; m < 4; ++m)                                                            \
            _Pragma("unroll")                                                                  \
            for (int n = 0; n < 2; ++n)                                                        \
                acc[m][n] = __builtin_amdgcn_mfma_f32_16x16x32_bf16(a[m], b[n], acc[m][n], 0, 0, 0); \
    }

    gld16(Ag,  Al0 + sOffA);
    gld16(Ag2, Al0 + sOffA2);
    gld16(Bg,  Bl0 + sOffB);
    __syncthreads();
    for (int t = 0; t < 32; t += 2) {
        if (t + 1 < 32) {
            int kn = (t + 1) * 32;
            gld16(Ag + kn,  Al1 + sOffA);
            gld16(Ag2 + kn, Al1 + sOffA2);
            gld16(Bg + kn,  Bl1 + sOffB);
        }
        GCOMPUTE2(Al0, Bl0)
        __syncthreads();
        if (t + 2 < 32) {
            int kn = (t + 2) * 32;
            gld16(Ag + kn,  Al0 + sOffA);
            gld16(Ag2 + kn, Al0 + sOffA2);
            gld16(Bg + kn,  Bl0 + sOffB);
        }
        GCOMPUTE2(Al1, Bl1)
        __syncthreads();
    }
#undef GCOMPUTE2

    float* FP = reinterpret_cast<float*>(POOL);
#pragma unroll
    for (int m = 0; m < 4; ++m)
#pragma unroll
        for (int n = 0; n < 2; ++n)
#pragma unroll
            for (int r = 0; r < 4; ++r) {
                int rl = wr * 64 + m * 16 + lg * 4 + r;
                int cl = wc * 32 + n * 16 + l15;
                FP[rl * 64 + cl] = acc[m][n][r];
            }
    __syncthreads();
    const int prow0 = tid >> 4;
    const int pcol4 = (tid & 15) * 4;
#pragma unroll
    for (int s = 0; s < 8; ++s) {
        int row = s * 16 + prow0;
        float4 vv = *reinterpret_cast<const float4*>(&FP[row * 64 + pcol4]);
        *reinterpret_cast<float4*>(&out[(size_t)(rowBase + row) * QD_ + colBase + pcol4]) = vv;
    }
}

// ---------------------------------------------------------------------------
// Attention R14: grid 512 (XCD-swizzled), 512 threads = 2 groups x 4 waves.
// Each wave owns 32 q-rows (qtile 128); group g sweeps kv [g*1024, +1024)
// against its own double-buffered K/V tiles (64 KB LDS POOL).
// R7 softmax: exp2 on pre-scaled Q, ones-MFMA row sums. f32 partial combine
// through LDS at the end (group 1 -> LDS, group 0 adds, normalizes, writes).
// ---------------------------------------------------------------------------
__global__ __launch_bounds__(512, 4) void attn_kernel(const __bf16* __restrict__ Q,
                                                      const __bf16* __restrict__ K,
                                                      const __bf16* __restrict__ Vt,
                                                      __bf16* __restrict__ AO) {
    __shared__ __align__(16) __bf16 POOL[32768];   // 64 KB

    const int logical = (blockIdx.x & 7) * 64 + (blockIdx.x >> 3);
    const int qt   = logical & 15;
    const int bh   = logical >> 4;
    const int b    = bh >> 4;
    const int h    = bh & 15;
    const int wid  = threadIdx.x >> 6;     // 0..7
    const int grp  = wid >> 2;             // 0,1: kv-range group
    const int wl   = wid & 3;              // wave within group
    const int lane = threadIdx.x & 63;
    const int l15  = lane & 15;
    const int lg   = lane >> 4;
    const int qbase = qt * 128 + wl * 32;
    const int kv0   = grp << 10;

    const __bf16* Qp = Q  + ((size_t)bh * N_ + qbase) * D_;
    const __bf16* Kp = K  + (size_t)bh * M_ * D_;
    const __bf16* Vp = Vt + (size_t)bh * D_ * M_;

    // ---- staging geometry (R13-verified, group-local wl) ----
    const int srow = (wl << 4) + (lane >> 3);       // group-tile row
    const int scol = (lane & 7) << 3;
    const int sk0  = (lane >> 3) & 3;               // sK(srow), bit3(srow)=0
    const int sk1  = sk0 | 4;                       // sK(srow+8)
    const int sv   = lane >> 3;                     // sV(srow)=sV(srow+8)
    const int kc0  = scol ^ (sk0 << 3);
    const int kc1  = scol ^ (sk1 << 3);
    const int vc   = scol ^ (sv  << 3);

    __bf16* const K0 = POOL + (grp * 2 + 0) * 4096;
    __bf16* const K1 = POOL + (grp * 2 + 1) * 4096;
    __bf16* const V0 = POOL + 16384 + (grp * 2 + 0) * 4096;
    __bf16* const V1 = POOL + 16384 + (grp * 2 + 1) * 4096;
    __bf16* const k0d = K0 + wl * 1024;
    __bf16* const k1d = K1 + wl * 1024;
    __bf16* const v0d = V0 + wl * 1024;
    __bf16* const v1d = V1 + wl * 1024;

#define STAGE(KD, VD, KV)                                                      \
    gld16(Kp + (size_t)((KV) + srow)     * D_ + kc0, (KD));                    \
    gld16(Kp + (size_t)((KV) + srow + 8) * D_ + kc1, (KD) + 512);              \
    gld16(Vp + (size_t)(srow)     * M_ + (KV) + vc,  (VD));                    \
    gld16(Vp + (size_t)(srow + 8) * M_ + (KV) + vc,  (VD) + 512);

    // ---- read geometry (R13-verified) ----
    const int rm0 = ((l15 >> 2) * 8) + (l15 & 3);
    const int skq = (l15 & 3) | (((l15 >> 2) & 1) << 2);
    const int svq = l15 & 7;
    const int ak00 = rm0 * 64 + (( 0 + lg * 8) ^ (skq << 3));
    const int ak01 = rm0 * 64 + ((32 + lg * 8) ^ (skq << 3));
    const int ak10 = ak00 + 256;
    const int ak11 = ak01 + 256;
    const int av0 = l15 * 64 + (( 0 + lg * 8) ^ (svq << 3));
    const int av1 = l15 * 64 + ((32 + lg * 8) ^ (svq << 3));

    // Q fragments (B-operand), two q-groups of 16 rows
    bf16x8 qf00 = *reinterpret_cast<const bf16x8*>(Qp + (size_t)(l15)      * D_ +      lg * 8);
    bf16x8 qf01 = *reinterpret_cast<const bf16x8*>(Qp + (size_t)(l15)      * D_ + 32 + lg * 8);
    bf16x8 qf10 = *reinterpret_cast<const bf16x8*>(Qp + (size_t)(16 + l15) * D_ +      lg * 8);
    bf16x8 qf11 = *reinterpret_cast<const bf16x8*>(Qp + (size_t)(16 + l15) * D_ + 32 + lg * 8);

    bf16x8 onesf;
#pragma unroll
    for (int j = 0; j < 8; ++j) onesf[j] = (__bf16)1.0f;

    f32x4 o00 = {}, o01 = {}, o10 = {}, o11 = {};
    f32x4 o20 = {}, o21 = {}, o30 = {}, o31 = {};
    f32x4 ors0 = {}, ors1 = {};

#define COMPUTE(KB, VB, KOFF, AV)                                                               \
    {                                                                                           \
        bf16x8 k00 = *reinterpret_cast<const bf16x8*>((KB) + ak00 + (KOFF));                    \
        bf16x8 k01 = *reinterpret_cast<const bf16x8*>((KB) + ak01 + (KOFF));                    \
        bf16x8 k10 = *reinterpret_cast<const bf16x8*>((KB) + ak10 + (KOFF));                    \
        bf16x8 k11 = *reinterpret_cast<const bf16x8*>((KB) + ak11 + (KOFF));                    \
        bf16x8 v0  = *reinterpret_cast<const bf16x8*>((VB) + (AV));                             \
        bf16x8 v1  = *reinterpret_cast<const bf16x8*>((VB) + (AV) + 1024);                      \
        bf16x8 v2  = *reinterpret_cast<const bf16x8*>((VB) + (AV) + 2048);                      \
        bf16x8 v3  = *reinterpret_cast<const bf16x8*>((VB) + (AV) + 3072);                      \
        f32x4 s00 = {}, s01 = {}, s10 = {}, s11 = {};                                           \
        s00 = __builtin_amdgcn_mfma_f32_16x16x32_bf16(k00, qf00, s00, 0, 0, 0);                 \
        s00 = __builtin_amdgcn_mfma_f32_16x16x32_bf16(k01, qf01, s00, 0, 0, 0);                 \
        s01 = __builtin_amdgcn_mfma_f32_16x16x32_bf16(k00, qf10, s01, 0, 0, 0);                 \
        s01 = __builtin_amdgcn_mfma_f32_16x16x32_bf16(k01, qf11, s01, 0, 0, 0);                 \
        s10 = __builtin_amdgcn_mfma_f32_16x16x32_bf16(k10, qf00, s10, 0, 0, 0);                 \
        s10 = __builtin_amdgcn_mfma_f32_16x16x32_bf16(k11, qf01, s10, 0, 0, 0);                 \
        s11 = __builtin_amdgcn_mfma_f32_16x16x32_bf16(k10, qf10, s11, 0, 0, 0);                 \
        s11 = __builtin_amdgcn_mfma_f32_16x16x32_bf16(k11, qf11, s11, 0, 0, 0);                 \
        bf16x8 pf0, pf1;                                                                        \
        pf0[0] = (__bf16)__builtin_amdgcn_exp2f(s00[0]);                                        \
        pf0[1] = (__bf16)__builtin_amdgcn_exp2f(s00[1]);                                        \
        pf0[2] = (__bf16)__builtin_amdgcn_exp2f(s00[2]);                                        \
        pf0[3] = (__bf16)__builtin_amdgcn_exp2f(s00[3]);                                        \
        pf0[4] = (__bf16)__builtin_amdgcn_exp2f(s10[0]);                                        \
        pf0[5] = (__bf16)__builtin_amdgcn_exp2f(s10[1]);                                        \
        pf0[6] = (__bf16)__builtin_amdgcn_exp2f(s10[2]);                                        \
        pf0[7] = (__bf16)__builtin_amdgcn_exp2f(s10[3]);                                        \
        pf1[0] = (__bf16)__builtin_amdgcn_exp2f(s01[0]);                                        \
        pf1[1] = (__bf16)__builtin_amdgcn_exp2f(s01[1]);                                        \
        pf1[2] = (__bf16)__builtin_amdgcn_exp2f(s01[2]);                                        \
        pf1[3] = (__bf16)__builtin_amdgcn_exp2f(s01[3]);                                        \
        pf1[4] = (__bf16)__builtin_amdgcn_exp2f(s11[0]);                                        \
        pf1[5] = (__bf16)__builtin_amdgcn_exp2f(s11[1]);                                        \
        pf1[6] = (__bf16)__builtin_amdgcn_exp2f(s11[2]);                                        \
        pf1[7] = (__bf16)__builtin_amdgcn_exp2f(s11[3]);                                        \
        ors0 = __builtin_amdgcn_mfma_f32_16x16x32_bf16(pf0, onesf, ors0, 0, 0, 0);              \
        ors1 = __builtin_amdgcn_mfma_f32_16x16x32_bf16(pf1, onesf, ors1, 0, 0, 0);              \
        o00 = __builtin_amdgcn_mfma_f32_16x16x32_bf16(pf0, v0, o00, 0, 0, 0);                   \
        o01 = __builtin_amdgcn_mfma_f32_16x16x32_bf16(pf1, v0, o01, 0, 0, 0);                   \
        o10 = __builtin_amdgcn_mfma_f32_16x16x32_bf16(pf0, v1, o10, 0, 0, 0);                   \
        o11 = __builtin_amdgcn_mfma_f32_16x16x32_bf16(pf1, v1, o11, 0, 0, 0);                   \
        o20 = __builtin_amdgcn_mfma_f32_16x16x32_bf16(pf0, v2, o20, 0, 0, 0);                   \
        o21 = __builtin_amdgcn_mfma_f32_16x16x32_bf16(pf1, v2, o21, 0, 0, 0);                   \
        o30 = __builtin_amdgcn_mfma_f32_16x16x32_bf16(pf0, v3, o30, 0, 0, 0);                   \
        o31 = __builtin_amdgcn_mfma_f32_16x16x32_bf16(pf1, v3, o31, 0, 0, 0);                   \
    }

    STAGE(k0d, v0d, kv0)
    __syncthreads();

    for (int t = 0; t < 16; t += 2) {
        if (t + 1 < 16) { STAGE(k1d, v1d, kv0 + (t + 1) * 64) }
        COMPUTE(K0, V0, 0,    av0)
        COMPUTE(K0, V0, 2048, av1)
        __syncthreads();
        if (t + 2 < 16) { STAGE(k0d, v0d, kv0 + (t + 2) * 64) }
        COMPUTE(K1, V1, 0,    av0)
        COMPUTE(K1, V1, 2048, av1)
        __syncthreads();
    }
#undef STAGE
#undef COMPUTE

    // ---- combine partials: group 1 -> LDS (f32), group 0 adds + writes ----
    float* LO = reinterpret_cast<float*>(POOL);    // [128][65] f32 = 33280 B
    float* LS = LO + 128 * 65;                     // [128] f32 row sums
    if (grp == 1) {
#pragma unroll
        for (int r = 0; r < 4; ++r) {
            int row0 = wl * 32 + lg * 4 + r;
            int row1 = row0 + 16;
            LO[row0 * 65 +  0 + l15] = o00[r];
            LO[row0 * 65 + 16 + l15] = o10[r];
            LO[row0 * 65 + 32 + l15] = o20[r];
            LO[row0 * 65 + 48 + l15] = o30[r];
            LO[row1 * 65 +  0 + l15] = o01[r];
            LO[row1 * 65 + 16 + l15] = o11[r];
            LO[row1 * 65 + 32 + l15] = o21[r];
            LO[row1 * 65 + 48 + l15] = o31[r];
            if (l15 == 0) { LS[row0] = ors0[r]; LS[row1] = ors1[r]; }
        }
    }
    __syncthreads();
    if (grp == 0) {
#pragma unroll
        for (int r = 0; r < 4; ++r) {
            int row0 = wl * 32 + lg * 4 + r;
            int row1 = row0 + 16;
            float i0 = 1.0f / (ors0[r] + LS[row0]);
            float i1 = 1.0f / (ors1[r] + LS[row1]);
            size_t g0 = ((size_t)b * N_ + qbase + lg * 4 + r) * QD_ + h * D_ + l15;
            size_t g1 = ((size_t)b * N_ + qbase + 16 + lg * 4 + r) * QD_ + h * D_ + l15;
            AO[g0 +  0] = (__bf16)((o00[r] + LO[row0 * 65 +  0 + l15]) * i0);
            AO[g0 + 16] = (__bf16)((o10[r] + LO[row0 * 65 + 16 + l15]) * i0);
            AO[g0 + 32] = (__bf16)((o20[r] + LO[row0 * 65 + 32 + l15]) * i0);
            AO[g0 + 48] = (__bf16)((o30[r] + LO[row0 * 65 + 48 + l15]) * i0);
            AO[g1 +  0] = (__bf16)((o01[r] + LO[row1 * 65 +  0 + l15]) * i1);
            AO[g1 + 16] = (__bf16)((o11[r] + LO[row1 * 65 + 16 + l15]) * i1);
            AO[g1 + 32] = (__bf16)((o21[r] + LO[row1 * 65 + 32 + l15]) * i1);
            AO[g1 + 48] = (__bf16)((o31[r] + LO[row1 * 65 + 48 + l15]) * i1);
        }
    }
}

// ---------------------------------------------------------------------------
extern "C" void kernel_launch(void* const* d_in, const int* in_sizes, int n_in,
                              void* d_out, int out_size, void* d_ws, size_t ws_size,
                              hipStream_t stream) {
    const float* x   = (const float*)d_in[0];
    const float* ctx = (const float*)d_in[1];
    const float* Wq  = (const float*)d_in[2];
    const float* Wk  = (const float*)d_in[3];
    const float* Wv  = (const float*)d_in[4];
    const float* Wo  = (const float*)d_in[5];

    char* ws = (char*)d_ws;
    __bf16* xb  = (__bf16*)(ws);                      // 0-8 MB
    __bf16* cb  = (__bf16*)(ws + (8u  << 20));        // 8-16 MB
    __bf16* Wtq = (__bf16*)(ws + (16u << 20));        // 16-18 MB
    __bf16* Wtk = (__bf16*)(ws + (18u << 20));        // 18-20
    __bf16* Wtv = (__bf16*)(ws + (20u << 20));        // 20-22
    __bf16* Wto = (__bf16*)(ws + (22u << 20));        // 22-24
    __bf16* Qb  = (__bf16*)(ws + (24u << 20));        // 24-32  [bh][2048][64], pre-scaled
    __bf16* Kb  = (__bf16*)(ws + (32u << 20));        // 32-40  [bh][2048][64]
    __bf16* Vt  = (__bf16*)(ws + (40u << 20));        // 40-48  [bh][64][2048]
    __bf16* AO  = (__bf16*)(ws + (48u << 20));        // 48-56  [4096][1024]

    prep<<<dim3(16, 16, 6), 256, 0, stream>>>(x, ctx, Wq, Wk, Wv, Wo,
                                              xb, cb, Wtq, Wtk, Wtv, Wto);
    gemm_qkv<<<dim3(32, 8, 3), 256, 0, stream>>>(xb, cb, Wtq, Wtk, Wtv, Qb, Kb, Vt);
    attn_kernel<<<512, 512, 0, stream>>>(Qb, Kb, Vt, AO);
    gemm_out<<<dim3(32, 16), 256, 0, stream>>>(AO, Wto, (float*)d_out);
}

// Round 15
// 105.516 us; speedup vs baseline: 1.0784x; 1.0035x over previous
//
#include <hip/hip_runtime.h>
#include <hip/hip_bf16.h>

// ---------------------------------------------------------------------------
// CrossAttention: out = softmax((x Wq)(ctx Wk)^T * scale) (ctx Wv) Wo
// B=2, N=M=2048, H=16, D=64, QD=INNER=1024. fp32 in/out, bf16 MFMA inside.
// R15 = R14 + (1) padded repack strides in GEMM epilogues (136 bf16 / 68 f32
// rows = 272B, kills the 2.2M epilogue bank conflicts), (2) s_setprio(1)
// around attention MFMA clusters (T5; 2-group structure gives role diversity).
// ---------------------------------------------------------------------------

typedef __attribute__((ext_vector_type(8))) __bf16    bf16x8;
typedef __attribute__((ext_vector_type(4))) __bf16    bf16x4;
typedef __attribute__((ext_vector_type(4))) float     f32x4;

#define B_    2
#define H_    16
#define N_    2048
#define M_    2048
#define D_    64
#define QD_   1024

// 0.125 * log2(e): folds softmax scale and exp->exp2 conversion into Q
#define QSCALE 0.18033688011112042f

// direct global->LDS async copy, 16B per lane; LDS dest = wave-uniform base + lane*16
__device__ __forceinline__ void gld16(const __bf16* g, __bf16* l) {
    __builtin_amdgcn_global_load_lds(
        (const __attribute__((address_space(1))) unsigned int*)(g),
        (__attribute__((address_space(3))) unsigned int*)(l), 16, 0, 0);
}

// ---------------------------------------------------------------------------
// prep: z<2 -> f32->bf16 convert of x/ctx; z>=2 -> weight transpose+convert.
// ---------------------------------------------------------------------------
__global__ __launch_bounds__(256) void prep(const float* __restrict__ x,
                                            const float* __restrict__ ctx,
                                            const float* __restrict__ w0,
                                            const float* __restrict__ w1,
                                            const float* __restrict__ w2,
                                            const float* __restrict__ w3,
                                            __bf16* __restrict__ xb,
                                            __bf16* __restrict__ cb,
                                            __bf16* __restrict__ t0,
                                            __bf16* __restrict__ t1,
                                            __bf16* __restrict__ t2,
                                            __bf16* __restrict__ t3) {
    __shared__ float tile[64][65];
    const int z = blockIdx.z;
    if (z < 2) {
        const float* src = z ? ctx : x;
        __bf16*      dst = z ? cb  : xb;
        const size_t base = (size_t)(blockIdx.y * 16 + blockIdx.x) * 16384;
#pragma unroll
        for (int p = 0; p < 16; ++p) {
            size_t i = base + p * 1024 + threadIdx.x * 4;
            float4 v = *reinterpret_cast<const float4*>(src + i);
            bf16x4 o;
            o.x = (__bf16)v.x; o.y = (__bf16)v.y; o.z = (__bf16)v.z; o.w = (__bf16)v.w;
            *reinterpret_cast<bf16x4*>(dst + i) = o;
        }
        return;
    }
    const int w = z - 2;
    const float* in = (w == 0) ? w0 : (w == 1) ? w1 : (w == 2) ? w2 : w3;
    __bf16*     out = (w == 0) ? t0 : (w == 1) ? t1 : (w == 2) ? t2 : t3;
    const int i0 = blockIdx.x * 64;
    const int o0 = blockIdx.y * 64;
    const int t  = threadIdx.x;
    const int r  = t >> 4;
    const int c4 = (t & 15) * 4;
#pragma unroll
    for (int p = 0; p < 4; ++p) {
        int row = p * 16 + r;
        float4 v = *reinterpret_cast<const float4*>(in + (size_t)(i0 + row) * QD_ + o0 + c4);
        tile[row][c4 + 0] = v.x; tile[row][c4 + 1] = v.y;
        tile[row][c4 + 2] = v.z; tile[row][c4 + 3] = v.w;
    }
    __syncthreads();
#pragma unroll
    for (int p = 0; p < 4; ++p) {
        int orow = p * 16 + r;
        bf16x4 o;
        o.x = (__bf16)tile[c4 + 0][orow];
        o.y = (__bf16)tile[c4 + 1][orow];
        o.z = (__bf16)tile[c4 + 2][orow];
        o.w = (__bf16)tile[c4 + 3][orow];
        *reinterpret_cast<bf16x4*>(out + (size_t)(o0 + orow) * QD_ + i0 + c4) = o;
    }
}

// ---------------------------------------------------------------------------
// gemm_qkv: 128x128 tile, stage-ahead dbuf via gld16, XOR swizzle,
// LDS-pool repack epilogue (V transposed), PADDED stride 136 (R15).
// ---------------------------------------------------------------------------
__global__ __launch_bounds__(256) void gemm_qkv(const __bf16* __restrict__ xb,
                                                const __bf16* __restrict__ cb,
                                                const __bf16* __restrict__ Wtq,
                                                const __bf16* __restrict__ Wtk,
                                                const __bf16* __restrict__ Wtv,
                                                __bf16* __restrict__ Qb,
                                                __bf16* __restrict__ Kb,
                                                __bf16* __restrict__ Vt) {
    __shared__ __align__(16) __bf16 POOL[17408];   // max(staging 16384, repack 128*136)
    __bf16* const Al0 = POOL;
    __bf16* const Al1 = POOL + 4096;
    __bf16* const Bl0 = POOL + 8192;
    __bf16* const Bl1 = POOL + 12288;

    const int z = blockIdx.z;
    const __bf16* A_  = (z == 0) ? xb : cb;
    const __bf16* Bt_ = (z == 0) ? Wtq : (z == 1) ? Wtk : Wtv;

    const int tid  = threadIdx.x;
    const int wid  = tid >> 6;
    const int lane = tid & 63;
    const int l15  = lane & 15;
    const int lg   = lane >> 4;
    const int wr   = wid >> 1;
    const int wc   = wid & 1;
    const int rowBase = blockIdx.x * 128;
    const int colBase = blockIdx.y * 128;
    const int srow = wid * 32 + (lane >> 2);
    const int sg   = ((lane & 3) ^ ((srow >> 1) & 3)) * 8;  // pre-swizzled src granule
    const __bf16* Ag  = A_  + (size_t)(rowBase + srow) * QD_ + sg;
    const __bf16* Ag2 = Ag  + (size_t)16 * QD_;
    const __bf16* Bg  = Bt_ + (size_t)(colBase + srow) * QD_ + sg;
    const __bf16* Bg2 = Bg  + (size_t)16 * QD_;
    const int sOff  = (wid * 32) * 32;
    const int sOff2 = sOff + 16 * 32;
    int aoff[4], boff[4];
#pragma unroll
    for (int m = 0; m < 4; ++m) {
        int ra = wr * 64 + m * 16 + l15;
        int rb = wc * 64 + m * 16 + l15;
        aoff[m] = ra * 32 + ((lg ^ ((ra >> 1) & 3)) * 8);
        boff[m] = rb * 32 + ((lg ^ ((rb >> 1) & 3)) * 8);
    }
    f32x4 acc[4][4] = {};

#define GCOMPUTE(AL, BL)                                                                       \
    {                                                                                          \
        bf16x8 a[4], b[4];                                                                     \
        _Pragma("unroll")                                                                      \
        for (int m = 0; m < 4; ++m)                                                            \
            a[m] = *reinterpret_cast<const bf16x8*>(&(AL)[aoff[m]]);                           \
        _Pragma("unroll")                                                                      \
        for (int n = 0; n < 4; ++n)                                                            \
            b[n] = *reinterpret_cast<const bf16x8*>(&(BL)[boff[n]]);                           \
        _Pragma("unroll")                                                                      \
        for (int m = 0; m < 4; ++m)                                                            \
            _Pragma("unroll")                                                                  \
            for (int n = 0; n < 4; ++n)                                                        \
                acc[m][n] = __builtin_amdgcn_mfma_f32_16x16x32_bf16(a[m], b[n], acc[m][n], 0, 0, 0); \
    }

    gld16(Ag,  Al0 + sOff);
    gld16(Ag2, Al0 + sOff2);
    gld16(Bg,  Bl0 + sOff);
    gld16(Bg2, Bl0 + sOff2);
    __syncthreads();
    for (int t = 0; t < 32; t += 2) {
        if (t + 1 < 32) {
            int kn = (t + 1) * 32;
            gld16(Ag + kn,  Al1 + sOff);
            gld16(Ag2 + kn, Al1 + sOff2);
            gld16(Bg + kn,  Bl1 + sOff);
            gld16(Bg2 + kn, Bl1 + sOff2);
        }
        GCOMPUTE(Al0, Bl0)
        __syncthreads();
        if (t + 2 < 32) {
            int kn = (t + 2) * 32;
            gld16(Ag + kn,  Al0 + sOff);
            gld16(Ag2 + kn, Al0 + sOff2);
            gld16(Bg + kn,  Bl0 + sOff);
            gld16(Bg2 + kn, Bl0 + sOff2);
        }
        GCOMPUTE(Al1, Bl1)
        __syncthreads();
    }
#undef GCOMPUTE

    // epilogue: repack into POOL (V transposed), PADDED stride 136
#pragma unroll
    for (int m = 0; m < 4; ++m)
#pragma unroll
        for (int n = 0; n < 4; ++n)
#pragma unroll
            for (int r = 0; r < 4; ++r) {
                float v = acc[m][n][r];
                if (z == 0) v *= QSCALE;
                int rl = wr * 64 + m * 16 + lg * 4 + r;
                int cl = wc * 64 + n * 16 + l15;
                if (z == 2) POOL[cl * 136 + rl] = (__bf16)v;   // [d-col][token]
                else        POOL[rl * 136 + cl] = (__bf16)v;   // [token][d-col]
            }
    __syncthreads();

    const int prow0 = tid >> 4;         // 0..15
    const int pcol  = (tid & 15) * 8;   // 0..120
#pragma unroll
    for (int s = 0; s < 8; ++s) {
        int row = s * 16 + prow0;
        bf16x8 vv = *reinterpret_cast<const bf16x8*>(&POOL[row * 136 + pcol]);
        if (z == 2) {
            int cc = colBase + row, rr = rowBase + pcol;
            int b_ = rr >> 11, mm = rr & 2047, hh = cc >> 6, dd = cc & 63;
            *reinterpret_cast<bf16x8*>(&Vt[((size_t)(b_ * H_ + hh) * D_ + dd) * M_ + mm]) = vv;
        } else {
            int rr = rowBase + row, cc = colBase + pcol;
            int b_ = rr >> 11, nn = rr & 2047, hh = cc >> 6, dd = cc & 63;
            __bf16* dst = (z == 0) ? Qb : Kb;
            *reinterpret_cast<bf16x8*>(&dst[((size_t)(b_ * H_ + hh) * N_ + nn) * D_ + dd]) = vv;
        }
    }
}

// ---------------------------------------------------------------------------
// gemm_out: 128x64 tile, stage-ahead dbuf + swizzle, f32 repack PAD 68 (R15).
// ---------------------------------------------------------------------------
__global__ __launch_bounds__(256) void gemm_out(const __bf16* __restrict__ AO,
                                                const __bf16* __restrict__ Wto,
                                                float* __restrict__ out) {
    __shared__ __align__(16) __bf16 POOL[17408];   // staging 12288; repack 128*68 f32
    __bf16* const Al0 = POOL;
    __bf16* const Al1 = POOL + 4096;
    __bf16* const Bl0 = POOL + 8192;
    __bf16* const Bl1 = POOL + 10240;

    const int tid  = threadIdx.x;
    const int wid  = tid >> 6;
    const int lane = tid & 63;
    const int l15  = lane & 15;
    const int lg   = lane >> 4;
    const int wr   = wid >> 1;
    const int wc   = wid & 1;
    const int rowBase = blockIdx.x * 128;
    const int colBase = blockIdx.y * 64;
    const int srowA = wid * 32 + (lane >> 2);
    const int srowB = wid * 16 + (lane >> 2);
    const int sgA   = ((lane & 3) ^ ((srowA >> 1) & 3)) * 8;
    const int sgB   = ((lane & 3) ^ ((srowB >> 1) & 3)) * 8;
    const __bf16* Ag  = AO  + (size_t)(rowBase + srowA) * QD_ + sgA;
    const __bf16* Ag2 = Ag  + (size_t)16 * QD_;
    const __bf16* Bg  = Wto + (size_t)(colBase + srowB) * QD_ + sgB;
    const int sOffA  = (wid * 32) * 32;
    const int sOffA2 = sOffA + 16 * 32;
    const int sOffB  = (wid * 16) * 32;
    int aoff[4], boff[2];
#pragma unroll
    for (int m = 0; m < 4; ++m) {
        int ra = wr * 64 + m * 16 + l15;
        aoff[m] = ra * 32 + ((lg ^ ((ra >> 1) & 3)) * 8);
    }
#pragma unroll
    for (int n = 0; n < 2; ++n) {
        int rb = wc * 32 + n * 16 + l15;
        boff[n] = rb * 32 + ((lg ^ ((rb >> 1) & 3)) * 8);
    }
    f32x4 acc[4][2] = {};

#define GCOMPUTE2(AL, BL)                                                                      \
    {                                                                                          \
        bf16x8 a[4], b[2];                                                                     \
        _Pragma("unroll")                                                                      \
        for (int m = 0; m < 4; ++m)                                                            \
            a[m] = *reinterpret_cast<const bf16x8*>(&(AL)[aoff[m]]);                           \
        _Pragma("unroll")                                                                      \
        for (int n = 0; n < 2; ++n)                                                            \
            b[n] = *reinterpret_cast<const bf16x8*>(&(BL)[boff[n]]);                           \
        _Pragma("unroll")                                                                      \
        for (int m = 0; m < 4; ++m)                                                            \
            _Pragma("unroll")                                                                  \
            for (int n = 0; n < 2; ++n)                                                        \
                acc[m][n] = __builtin_amdgcn_mfma_f32_16x16x32_bf16(a[m], b[n], acc[m][n], 0, 0, 0); \
    }

    gld16(Ag,  Al0 + sOffA);
    gld16(Ag2, Al0 + sOffA2);
    gld16(Bg,  Bl0 + sOffB);
    __syncthreads();
    for (int t = 0; t < 32; t += 2) {
        if (t + 1 < 32) {
            int kn = (t + 1) * 32;
            gld16(Ag + kn,  Al1 + sOffA);
            gld16(Ag2 + kn, Al1 + sOffA2);
            gld16(Bg + kn,  Bl1 + sOffB);
        }
        GCOMPUTE2(Al0, Bl0)
        __syncthreads();
        if (t + 2 < 32) {
            int kn = (t + 2) * 32;
            gld16(Ag + kn,  Al0 + sOffA);
            gld16(Ag2 + kn, Al0 + sOffA2);
            gld16(Bg + kn,  Bl0 + sOffB);
        }
        GCOMPUTE2(Al1, Bl1)
        __syncthreads();
    }
#undef GCOMPUTE2

    float* FP = reinterpret_cast<float*>(POOL);
#pragma unroll
    for (int m = 0; m < 4; ++m)
#pragma unroll
        for (int n = 0; n < 2; ++n)
#pragma unroll
            for (int r = 0; r < 4; ++r) {
                int rl = wr * 64 + m * 16 + lg * 4 + r;
                int cl = wc * 32 + n * 16 + l15;
                FP[rl * 68 + cl] = acc[m][n][r];
            }
    __syncthreads();
    const int prow0 = tid >> 4;
    const int pcol4 = (tid & 15) * 4;
#pragma unroll
    for (int s = 0; s < 8; ++s) {
        int row = s * 16 + prow0;
        float4 vv = *reinterpret_cast<const float4*>(&FP[row * 68 + pcol4]);
        *reinterpret_cast<float4*>(&out[(size_t)(rowBase + row) * QD_ + colBase + pcol4]) = vv;
    }
}

// ---------------------------------------------------------------------------
// Attention (R14 + T5 setprio): grid 512 (XCD-swizzled), 512 threads =
// 2 groups x 4 waves; each wave 32 q-rows; group g sweeps kv [g*1024,+1024)
// with its own dbuf K/V tiles (64 KB). exp2 softmax, ones-MFMA row sums,
// f32 partial combine via LDS.
// ---------------------------------------------------------------------------
__global__ __launch_bounds__(512, 4) void attn_kernel(const __bf16* __restrict__ Q,
                                                      const __bf16* __restrict__ K,
                                                      const __bf16* __restrict__ Vt,
                                                      __bf16* __restrict__ AO) {
    __shared__ __align__(16) __bf16 POOL[32768];   // 64 KB

    const int logical = (blockIdx.x & 7) * 64 + (blockIdx.x >> 3);
    const int qt   = logical & 15;
    const int bh   = logical >> 4;
    const int b    = bh >> 4;
    const int h    = bh & 15;
    const int wid  = threadIdx.x >> 6;     // 0..7
    const int grp  = wid >> 2;             // 0,1: kv-range group
    const int wl   = wid & 3;              // wave within group
    const int lane = threadIdx.x & 63;
    const int l15  = lane & 15;
    const int lg   = lane >> 4;
    const int qbase = qt * 128 + wl * 32;
    const int kv0   = grp << 10;

    const __bf16* Qp = Q  + ((size_t)bh * N_ + qbase) * D_;
    const __bf16* Kp = K  + (size_t)bh * M_ * D_;
    const __bf16* Vp = Vt + (size_t)bh * D_ * M_;

    const int srow = (wl << 4) + (lane >> 3);
    const int scol = (lane & 7) << 3;
    const int sk0  = (lane >> 3) & 3;
    const int sk1  = sk0 | 4;
    const int sv   = lane >> 3;
    const int kc0  = scol ^ (sk0 << 3);
    const int kc1  = scol ^ (sk1 << 3);
    const int vc   = scol ^ (sv  << 3);

    __bf16* const K0 = POOL + (grp * 2 + 0) * 4096;
    __bf16* const K1 = POOL + (grp * 2 + 1) * 4096;
    __bf16* const V0 = POOL + 16384 + (grp * 2 + 0) * 4096;
    __bf16* const V1 = POOL + 16384 + (grp * 2 + 1) * 4096;
    __bf16* const k0d = K0 + wl * 1024;
    __bf16* const k1d = K1 + wl * 1024;
    __bf16* const v0d = V0 + wl * 1024;
    __bf16* const v1d = V1 + wl * 1024;

#define STAGE(KD, VD, KV)                                                      \
    gld16(Kp + (size_t)((KV) + srow)     * D_ + kc0, (KD));                    \
    gld16(Kp + (size_t)((KV) + srow + 8) * D_ + kc1, (KD) + 512);              \
    gld16(Vp + (size_t)(srow)     * M_ + (KV) + vc,  (VD));                    \
    gld16(Vp + (size_t)(srow + 8) * M_ + (KV) + vc,  (VD) + 512);

    const int rm0 = ((l15 >> 2) * 8) + (l15 & 3);
    const int skq = (l15 & 3) | (((l15 >> 2) & 1) << 2);
    const int svq = l15 & 7;
    const int ak00 = rm0 * 64 + (( 0 + lg * 8) ^ (skq << 3));
    const int ak01 = rm0 * 64 + ((32 + lg * 8) ^ (skq << 3));
    const int ak10 = ak00 + 256;
    const int ak11 = ak01 + 256;
    const int av0 = l15 * 64 + (( 0 + lg * 8) ^ (svq << 3));
    const int av1 = l15 * 64 + ((32 + lg * 8) ^ (svq << 3));

    bf16x8 qf00 = *reinterpret_cast<const bf16x8*>(Qp + (size_t)(l15)      * D_ +      lg * 8);
    bf16x8 qf01 = *reinterpret_cast<const bf16x8*>(Qp + (size_t)(l15)      * D_ + 32 + lg * 8);
    bf16x8 qf10 = *reinterpret_cast<const bf16x8*>(Qp + (size_t)(16 + l15) * D_ +      lg * 8);
    bf16x8 qf11 = *reinterpret_cast<const bf16x8*>(Qp + (size_t)(16 + l15) * D_ + 32 + lg * 8);

    bf16x8 onesf;
#pragma unroll
    for (int j = 0; j < 8; ++j) onesf[j] = (__bf16)1.0f;

    f32x4 o00 = {}, o01 = {}, o10 = {}, o11 = {};
    f32x4 o20 = {}, o21 = {}, o30 = {}, o31 = {};
    f32x4 ors0 = {}, ors1 = {};

#define COMPUTE(KB, VB, KOFF, AV)                                                               \
    {                                                                                           \
        bf16x8 k00 = *reinterpret_cast<const bf16x8*>((KB) + ak00 + (KOFF));                    \
        bf16x8 k01 = *reinterpret_cast<const bf16x8*>((KB) + ak01 + (KOFF));                    \
        bf16x8 k10 = *reinterpret_cast<const bf16x8*>((KB) + ak10 + (KOFF));                    \
        bf16x8 k11 = *reinterpret_cast<const bf16x8*>((KB) + ak11 + (KOFF));                    \
        bf16x8 v0  = *reinterpret_cast<const bf16x8*>((VB) + (AV));                             \
        bf16x8 v1  = *reinterpret_cast<const bf16x8*>((VB) + (AV) + 1024);                      \
        bf16x8 v2  = *reinterpret_cast<const bf16x8*>((VB) + (AV) + 2048);                      \
        bf16x8 v3  = *reinterpret_cast<const bf16x8*>((VB) + (AV) + 3072);                      \
        f32x4 s00 = {}, s01 = {}, s10 = {}, s11 = {};                                           \
        __builtin_amdgcn_s_setprio(1);                                                          \
        s00 = __builtin_amdgcn_mfma_f32_16x16x32_bf16(k00, qf00, s00, 0, 0, 0);                 \
        s00 = __builtin_amdgcn_mfma_f32_16x16x32_bf16(k01, qf01, s00, 0, 0, 0);                 \
        s01 = __builtin_amdgcn_mfma_f32_16x16x32_bf16(k00, qf10, s01, 0, 0, 0);                 \
        s01 = __builtin_amdgcn_mfma_f32_16x16x32_bf16(k01, qf11, s01, 0, 0, 0);                 \
        s10 = __builtin_amdgcn_mfma_f32_16x16x32_bf16(k10, qf00, s10, 0, 0, 0);                 \
        s10 = __builtin_amdgcn_mfma_f32_16x16x32_bf16(k11, qf01, s10, 0, 0, 0);                 \
        s11 = __builtin_amdgcn_mfma_f32_16x16x32_bf16(k10, qf10, s11, 0, 0, 0);                 \
        s11 = __builtin_amdgcn_mfma_f32_16x16x32_bf16(k11, qf11, s11, 0, 0, 0);                 \
        __builtin_amdgcn_s_setprio(0);                                                          \
        bf16x8 pf0, pf1;                                                                        \
        pf0[0] = (__bf16)__builtin_amdgcn_exp2f(s00[0]);                                        \
        pf0[1] = (__bf16)__builtin_amdgcn_exp2f(s00[1]);                                        \
        pf0[2] = (__bf16)__builtin_amdgcn_exp2f(s00[2]);                                        \
        pf0[3] = (__bf16)__builtin_amdgcn_exp2f(s00[3]);                                        \
        pf0[4] = (__bf16)__builtin_amdgcn_exp2f(s10[0]);                                        \
        pf0[5] = (__bf16)__builtin_amdgcn_exp2f(s10[1]);                                        \
        pf0[6] = (__bf16)__builtin_amdgcn_exp2f(s10[2]);                                        \
        pf0[7] = (__bf16)__builtin_amdgcn_exp2f(s10[3]);                                        \
        pf1[0] = (__bf16)__builtin_amdgcn_exp2f(s01[0]);                                        \
        pf1[1] = (__bf16)__builtin_amdgcn_exp2f(s01[1]);                                        \
        pf1[2] = (__bf16)__builtin_amdgcn_exp2f(s01[2]);                                        \
        pf1[3] = (__bf16)__builtin_amdgcn_exp2f(s01[3]);                                        \
        pf1[4] = (__bf16)__builtin_amdgcn_exp2f(s11[0]);                                        \
        pf1[5] = (__bf16)__builtin_amdgcn_exp2f(s11[1]);                                        \
        pf1[6] = (__bf16)__builtin_amdgcn_exp2f(s11[2]);                                        \
        pf1[7] = (__bf16)__builtin_amdgcn_exp2f(s11[3]);                                        \
        __builtin_amdgcn_s_setprio(1);                                                          \
        ors0 = __builtin_amdgcn_mfma_f32_16x16x32_bf16(pf0, onesf, ors0, 0, 0, 0);              \
        ors1 = __builtin_amdgcn_mfma_f32_16x16x32_bf16(pf1, onesf, ors1, 0, 0, 0);              \
        o00 = __builtin_amdgcn_mfma_f32_16x16x32_bf16(pf0, v0, o00, 0, 0, 0);                   \
        o01 = __builtin_amdgcn_mfma_f32_16x16x32_bf16(pf1, v0, o01, 0, 0, 0);                   \
        o10 = __builtin_amdgcn_mfma_f32_16x16x32_bf16(pf0, v1, o10, 0, 0, 0);                   \
        o11 = __builtin_amdgcn_mfma_f32_16x16x32_bf16(pf1, v1, o11, 0, 0, 0);                   \
        o20 = __builtin_amdgcn_mfma_f32_16x16x32_bf16(pf0, v2, o20, 0, 0, 0);                   \
        o21 = __builtin_amdgcn_mfma_f32_16x16x32_bf16(pf1, v2, o21, 0, 0, 0);                   \
        o30 = __builtin_amdgcn_mfma_f32_16x16x32_bf16(pf0, v3, o30, 0, 0, 0);                   \
        o31 = __builtin_amdgcn_mfma_f32_16x16x32_bf16(pf1, v3, o31, 0, 0, 0);                   \
        __builtin_amdgcn_s_setprio(0);                                                          \
    }

    STAGE(k0d, v0d, kv0)
    __syncthreads();

    for (int t = 0; t < 16; t += 2) {
        if (t + 1 < 16) { STAGE(k1d, v1d, kv0 + (t + 1) * 64) }
        COMPUTE(K0, V0, 0,    av0)
        COMPUTE(K0, V0, 2048, av1)
        __syncthreads();
        if (t + 2 < 16) { STAGE(k0d, v0d, kv0 + (t + 2) * 64) }
        COMPUTE(K1, V1, 0,    av0)
        COMPUTE(K1, V1, 2048, av1)
        __syncthreads();
    }
#undef STAGE
#undef COMPUTE

    // combine partials: group 1 -> LDS (f32), group 0 adds + writes
    float* LO = reinterpret_cast<float*>(POOL);    // [128][65] f32
    float* LS = LO + 128 * 65;                     // [128] f32 row sums
    if (grp == 1) {
#pragma unroll
        for (int r = 0; r < 4; ++r) {
            int row0 = wl * 32 + lg * 4 + r;
            int row1 = row0 + 16;
            LO[row0 * 65 +  0 + l15] = o00[r];
            LO[row0 * 65 + 16 + l15] = o10[r];
            LO[row0 * 65 + 32 + l15] = o20[r];
            LO[row0 * 65 + 48 + l15] = o30[r];
            LO[row1 * 65 +  0 + l15] = o01[r];
            LO[row1 * 65 + 16 + l15] = o11[r];
            LO[row1 * 65 + 32 + l15] = o21[r];
            LO[row1 * 65 + 48 + l15] = o31[r];
            if (l15 == 0) { LS[row0] = ors0[r]; LS[row1] = ors1[r]; }
        }
    }
    __syncthreads();
    if (grp == 0) {
#pragma unroll
        for (int r = 0; r < 4; ++r) {
            int row0 = wl * 32 + lg * 4 + r;
            int row1 = row0 + 16;
            float i0 = 1.0f / (ors0[r] + LS[row0]);
            float i1 = 1.0f / (ors1[r] + LS[row1]);
            size_t g0 = ((size_t)b * N_ + qbase + lg * 4 + r) * QD_ + h * D_ + l15;
            size_t g1 = ((size_t)b * N_ + qbase + 16 + lg * 4 + r) * QD_ + h * D_ + l15;
            AO[g0 +  0] = (__bf16)((o00[r] + LO[row0 * 65 +  0 + l15]) * i0);
            AO[g0 + 16] = (__bf16)((o10[r] + LO[row0 * 65 + 16 + l15]) * i0);
            AO[g0 + 32] = (__bf16)((o20[r] + LO[row0 * 65 + 32 + l15]) * i0);
            AO[g0 + 48] = (__bf16)((o30[r] + LO[row0 * 65 + 48 + l15]) * i0);
            AO[g1 +  0] = (__bf16)((o01[r] + LO[row1 * 65 +  0 + l15]) * i1);
            AO[g1 + 16] = (__bf16)((o11[r] + LO[row1 * 65 + 16 + l15]) * i1);
            AO[g1 + 32] = (__bf16)((o21[r] + LO[row1 * 65 + 32 + l15]) * i1);
            AO[g1 + 48] = (__bf16)((o31[r] + LO[row1 * 65 + 48 + l15]) * i1);
        }
    }
}

// ---------------------------------------------------------------------------
extern "C" void kernel_launch(void* const* d_in, const int* in_sizes, int n_in,
                              void* d_out, int out_size, void* d_ws, size_t ws_size,
                              hipStream_t stream) {
    const float* x   = (const float*)d_in[0];
    const float* ctx = (const float*)d_in[1];
    const float* Wq  = (const float*)d_in[2];
    const float* Wk  = (const float*)d_in[3];
    const float* Wv  = (const float*)d_in[4];
    const float* Wo  = (const float*)d_in[5];

    char* ws = (char*)d_ws;
    __bf16* xb  = (__bf16*)(ws);                      // 0-8 MB
    __bf16* cb  = (__bf16*)(ws + (8u  << 20));        // 8-16 MB
    __bf16* Wtq = (__bf16*)(ws + (16u << 20));        // 16-18 MB
    __bf16* Wtk = (__bf16*)(ws + (18u << 20));        // 18-20
    __bf16* Wtv = (__bf16*)(ws + (20u << 20));        // 20-22
    __bf16* Wto = (__bf16*)(ws + (22u << 20));        // 22-24
    __bf16* Qb  = (__bf16*)(ws + (24u << 20));        // 24-32  [bh][2048][64], pre-scaled
    __bf16* Kb  = (__bf16*)(ws + (32u << 20));        // 32-40  [bh][2048][64]
    __bf16* Vt  = (__bf16*)(ws + (40u << 20));        // 40-48  [bh][64][2048]
    __bf16* AO  = (__bf16*)(ws + (48u << 20));        // 48-56  [4096][1024]

    prep<<<dim3(16, 16, 6), 256, 0, stream>>>(x, ctx, Wq, Wk, Wv, Wo,
                                              xb, cb, Wtq, Wtk, Wtv, Wto);
    gemm_qkv<<<dim3(32, 8, 3), 256, 0, stream>>>(xb, cb, Wtq, Wtk, Wtv, Qb, Kb, Vt);
    attn_kernel<<<512, 512, 0, stream>>>(Qb, Kb, Vt, AO);
    gemm_out<<<dim3(32, 16), 256, 0, stream>>>(AO, Wto, (float*)d_out);
}